// Round 1
// baseline (1280.869 us; speedup 1.0000x reference)
//
#include <hip/hip_runtime.h>

#define HH 128
#define WW 224
#define HWN (HH * WW)   // 28672 = 112 * 256

__device__ __forceinline__ float lrelu_f(float v) { return v >= 0.f ? v : 0.1f * v; }

// Generic 3x3 conv, stride 1, pad 1. Thread = 1 pixel x 8 output channels.
// NIN = number of 64-channel input blocks (2 for the concat conv, 1 otherwise).
template<int NIN, bool LRELU>
__global__ __launch_bounds__(256)
void conv3_k(const float* __restrict__ x0, const float* __restrict__ x1,
             const float* __restrict__ w, const float* __restrict__ bias,
             float* __restrict__ out, int Cout) {
  const int tid = threadIdx.x;
  const int p = blockIdx.x * 256 + tid;           // pixel in image (exact: HWN = 112*256)
  const int y = p / WW;
  const int x = p % WW;
  const int oc0 = blockIdx.y * 8;
  const int b = blockIdx.z;
  const int CIN = NIN * 64;

  // Hoist tap offsets + validity (same for every input channel)
  int offs[9];
  bool okm[9];
  #pragma unroll
  for (int ky = 0; ky < 3; ++ky) {
    const int yy = y + ky - 1;
    const bool oky = (yy >= 0) & (yy < HH);
    #pragma unroll
    for (int kx = 0; kx < 3; ++kx) {
      const int xx = x + kx - 1;
      okm[ky * 3 + kx] = oky & (xx >= 0) & (xx < WW);
      offs[ky * 3 + kx] = yy * WW + xx;
    }
  }

  float acc[8];
  #pragma unroll
  for (int o = 0; o < 8; ++o) acc[o] = bias[oc0 + o];

  #pragma unroll 1
  for (int half = 0; half < NIN; ++half) {
    const float* src = (half ? x1 : x0) + b * 64 * HWN;
    const float* wb = w + (oc0 * CIN + half * 64) * 9;
    #pragma unroll 2
    for (int ci = 0; ci < 64; ++ci) {
      const float* sc = src + ci * HWN;
      float xv[9];
      #pragma unroll
      for (int k = 0; k < 9; ++k) xv[k] = okm[k] ? sc[offs[k]] : 0.f;
      const float* wc = wb + ci * 9;   // block-uniform -> scalar loads
      #pragma unroll
      for (int o = 0; o < 8; ++o) {
        #pragma unroll
        for (int k = 0; k < 9; ++k)
          acc[o] = fmaf(wc[o * CIN * 9 + k], xv[k], acc[o]);
      }
    }
  }

  float* dst = out + (b * Cout + oc0) * HWN + p;
  #pragma unroll
  for (int o = 0; o < 8; ++o) {
    float v = acc[o];
    if (LRELU) v = lrelu_f(v);
    dst[o * HWN] = v;
  }
}

// Transpose w_dcn [o][c][k] -> wt [(c*9+k)][o] so the o-loop reads contiguous scalars.
__global__ void wdcn_transpose(const float* __restrict__ w, float* __restrict__ wt) {
  int i = blockIdx.x * 256 + threadIdx.x;          // over 64*64*9 = 36864
  if (i >= 64 * 64 * 9) return;
  const int k = i % 9;
  const int c = (i / 9) % 64;
  const int o = i / (9 * 64);
  wt[(c * 9 + k) * 64 + o] = w[i];
}

// DCNv1: thread = 1 pixel, all 64 output channels accumulated in VGPRs.
__global__ __launch_bounds__(256)
void dcn_k(const float* __restrict__ xin,   // nbr_fea [B,64,H,W]
           const float* __restrict__ off,   // [B,72,H,W]
           const float* __restrict__ wt,    // [(c*9+k)][64]
           const float* __restrict__ bias,  // [64]
           float* __restrict__ out) {
  const int tid = threadIdx.x;
  const int p = blockIdx.x * 256 + tid;
  const int y = p / WW;
  const int x = p % WW;
  const int b = blockIdx.y;

  float acc[64];
  #pragma unroll
  for (int o = 0; o < 64; ++o) acc[o] = bias[o];

  const float* xb = xin + b * 64 * HWN;
  const float* offb = off + b * 72 * HWN + p;

  #pragma unroll 1
  for (int g = 0; g < 4; ++g) {
    #pragma unroll 1
    for (int k = 0; k < 9; ++k) {
      const float dy = offb[(g * 18 + k * 2) * HWN];
      const float dx = offb[(g * 18 + k * 2 + 1) * HWN];
      const float sy = dy + (float)(y - 1 + k / 3);
      const float sx = dx + (float)(x - 1 + k % 3);
      const float fy = floorf(sy);
      const float fx = floorf(sx);
      const int y0 = (int)fy;
      const int x0 = (int)fx;
      const float ay = sy - fy;
      const float ax = sx - fx;
      float w00 = (1.f - ay) * (1.f - ax);
      float w01 = (1.f - ay) * ax;
      float w10 = ay * (1.f - ax);
      float w11 = ay * ax;
      const bool vy0 = (y0 >= 0) & (y0 < HH);
      const bool vy1 = (y0 + 1 >= 0) & (y0 + 1 < HH);
      const bool vx0 = (x0 >= 0) & (x0 < WW);
      const bool vx1 = (x0 + 1 >= 0) & (x0 + 1 < WW);
      w00 = (vy0 & vx0) ? w00 : 0.f;
      w01 = (vy0 & vx1) ? w01 : 0.f;
      w10 = (vy1 & vx0) ? w10 : 0.f;
      w11 = (vy1 & vx1) ? w11 : 0.f;
      const int cy0 = min(max(y0, 0), HH - 1);
      const int cy1 = min(max(y0 + 1, 0), HH - 1);
      const int cx0 = min(max(x0, 0), WW - 1);
      const int cx1 = min(max(x0 + 1, 0), WW - 1);
      const int i00 = cy0 * WW + cx0;
      const int i01 = cy0 * WW + cx1;
      const int i10 = cy1 * WW + cx0;
      const int i11 = cy1 * WW + cx1;
      const float* cb = xb + g * 16 * HWN;
      #pragma unroll
      for (int c = 0; c < 16; ++c) {
        const float* ch = cb + c * HWN;
        const float s = w00 * ch[i00] + w01 * ch[i01] + w10 * ch[i10] + w11 * ch[i11];
        const float* wck = wt + ((g * 16 + c) * 9 + k) * 64;  // uniform -> s_load
        #pragma unroll
        for (int o = 0; o < 64; ++o)
          acc[o] = fmaf(wck[o], s, acc[o]);
      }
    }
  }

  float* dst = out + b * 64 * HWN + p;
  #pragma unroll
  for (int o = 0; o < 64; ++o)
    dst[o * HWN] = lrelu_f(acc[o]);
}

extern "C" void kernel_launch(void* const* d_in, const int* in_sizes, int n_in,
                              void* d_out, int out_size, void* d_ws, size_t ws_size,
                              hipStream_t stream) {
  const float* nbr   = (const float*)d_in[0];
  const float* ref   = (const float*)d_in[1];
  const float* w_co1 = (const float*)d_in[2];
  const float* b_co1 = (const float*)d_in[3];
  const float* w_m1  = (const float*)d_in[4];
  const float* b_m1  = (const float*)d_in[5];
  const float* w_m2  = (const float*)d_in[6];
  const float* b_m2  = (const float*)d_in[7];
  const float* w_m3  = (const float*)d_in[8];
  const float* b_m3  = (const float*)d_in[9];
  const float* w_dcn = (const float*)d_in[10];
  const float* b_dcn = (const float*)d_in[11];
  float* out = (float*)d_out;

  char* ws = (char*)d_ws;
  // ws0: 33,030,144 B (holds feat [B,64,HW] then off3 [B,72,HW])
  // ws1: 29,360,128 B (m1 out)
  // wt : 147,456 B (transposed dcn weights)
  float* ws0 = (float*)ws;
  float* ws1 = (float*)(ws + 33030144);
  float* wt  = (float*)(ws + 33030144 + 29360128);

  dim3 blk(256);
  // feat = lrelu(conv(concat(nbr, ref)))          -> ws0
  conv3_k<2, true><<<dim3(112, 8, 4), blk, 0, stream>>>(nbr, ref, w_co1, b_co1, ws0, 64);
  // off = lrelu(conv(feat))                        -> ws1
  conv3_k<1, true><<<dim3(112, 8, 4), blk, 0, stream>>>(ws0, nullptr, w_m1, b_m1, ws1, 64);
  // off = lrelu(conv(off))                         -> d_out (scratch)
  conv3_k<1, true><<<dim3(112, 8, 4), blk, 0, stream>>>(ws1, nullptr, w_m2, b_m2, out, 64);
  // off = conv(off)  (72 ch, no lrelu)             -> ws0
  conv3_k<1, false><<<dim3(112, 9, 4), blk, 0, stream>>>(out, nullptr, w_m3, b_m3, ws0, 72);
  // transpose dcn weights
  wdcn_transpose<<<dim3(144), blk, 0, stream>>>(w_dcn, wt);
  // out = lrelu(deform_conv(nbr, off))             -> d_out
  dcn_k<<<dim3(112, 4), blk, 0, stream>>>(nbr, ws0, wt, b_dcn, out);
}

// Round 2
// 922.016 us; speedup vs baseline: 1.3892x; 1.3892x over previous
//
#include <hip/hip_runtime.h>

#define HH 128
#define WW 224
#define HW_ (HH * WW)   // 28672

typedef short short8 __attribute__((ext_vector_type(8)));
typedef float f32x4 __attribute__((ext_vector_type(4)));

__device__ __forceinline__ float lrelu_f(float v) { return v >= 0.f ? v : 0.1f * v; }

__device__ __forceinline__ unsigned short f2bf(float f) {
  union { float f; unsigned u; } x; x.f = f;
  unsigned r = x.u + 0x7fff + ((x.u >> 16) & 1);   // RNE
  return (unsigned short)(r >> 16);
}
__device__ __forceinline__ float bf2f(unsigned short u) {
  union { unsigned u; float f; } x; x.u = ((unsigned)u) << 16; return x.f;
}

// ---- prep: concat(nbr,ref) -> channel-last bf16 x1t[b][p][128] ----
__global__ __launch_bounds__(256)
void prep_xt(const float* __restrict__ nbr, const float* __restrict__ ref,
             unsigned short* __restrict__ xt) {
  const int lane = threadIdx.x & 63;
  const int q = threadIdx.x >> 6;          // channel quarter (32 ch)
  const int p = blockIdx.x * 64 + lane;
  const int b = blockIdx.y;
  const int c0 = q * 32;
  const float* src = (c0 < 64) ? (nbr + ((size_t)b * 64 + c0) * HW_)
                               : (ref + ((size_t)b * 64 + (c0 - 64)) * HW_);
  unsigned short tmp[32];
  #pragma unroll
  for (int i = 0; i < 32; ++i) tmp[i] = f2bf(src[(size_t)i * HW_ + p]);
  unsigned short* dst = xt + ((size_t)b * HW_ + p) * 128 + c0;
  #pragma unroll
  for (int i = 0; i < 4; ++i)
    *(short8*)(dst + i * 8) = *(const short8*)(tmp + i * 8);
}

// ---- prep: conv weight [O][C][9] fp32 -> [9][Opad][C] bf16 (zero-pad o>=O) ----
__global__ void prep_w(const float* __restrict__ w, unsigned short* __restrict__ wt,
                       int O, int Opad, int C) {
  int idx = blockIdx.x * 256 + threadIdx.x;
  int total = Opad * C * 9;
  if (idx >= total) return;
  int c = idx % C;
  int o = (idx / C) % Opad;
  int k = idx / (C * Opad);
  float v = (o < O) ? w[((size_t)o * C + c) * 9 + k] : 0.f;
  wt[idx] = f2bf(v);
}

// ---- prep: dcn weight [O][C][9] -> [(c*9+k)][64] fp32 ----
__global__ void prep_wdcn(const float* __restrict__ w, float* __restrict__ wt) {
  int i = blockIdx.x * 256 + threadIdx.x;
  if (i >= 64 * 64 * 9) return;
  const int k = i % 9;
  const int c = (i / 9) % 64;
  const int o = i / (9 * 64);
  wt[(c * 9 + k) * 64 + o] = w[i];
}

// ---- implicit-GEMM 3x3 conv via MFMA. Block: 128 pixels x NFRAG*16 outputs ----
// xt: [b][p][CIN] bf16. wt: [9][NFRAG*16][CIN] bf16. out: [b][p][CROW] bf16.
template<int CIN, int NFRAG, int CROW, bool LRELU>
__global__ __launch_bounds__(256)
void conv_mfma(const unsigned short* __restrict__ xt, const unsigned short* __restrict__ wt,
               const float* __restrict__ bias, unsigned short* __restrict__ out, int coutReal) {
  const int lane = threadIdx.x & 63;
  const int wave = threadIdx.x >> 6;
  const int b = blockIdx.y;
  const int m_base = blockIdx.x * 128 + wave * 32;
  const int l15 = lane & 15;
  const int lg = lane >> 4;

  const int p0 = m_base + l15;        // frag-0 pixel (A row)
  const int p1 = p0 + 16;             // frag-1 pixel
  const int y0p = p0 / WW, x0p = p0 % WW;
  const int y1p = p1 / WW, x1p = p1 % WW;
  const unsigned short* xb = xt + (size_t)b * HW_ * CIN;

  f32x4 acc[2][NFRAG];
  #pragma unroll
  for (int mf = 0; mf < 2; ++mf)
    #pragma unroll
    for (int nf = 0; nf < NFRAG; ++nf) acc[mf][nf] = (f32x4){0.f, 0.f, 0.f, 0.f};

  #pragma unroll 1
  for (int k = 0; k < 9; ++k) {
    const int ky = k / 3 - 1, kx = k % 3 - 1;
    const bool v0 = ((unsigned)(y0p + ky) < HH) & ((unsigned)(x0p + kx) < WW);
    const bool v1 = ((unsigned)(y1p + ky) < HH) & ((unsigned)(x1p + kx) < WW);
    const int q0 = v0 ? (p0 + ky * WW + kx) : 0;
    const int q1 = v1 ? (p1 + ky * WW + kx) : 0;
    const unsigned short* a0p = xb + (size_t)q0 * CIN + lg * 8;
    const unsigned short* a1p = xb + (size_t)q1 * CIN + lg * 8;
    const unsigned short* wp = wt + ((size_t)k * (NFRAG * 16) + l15) * CIN + lg * 8;
    #pragma unroll
    for (int cb = 0; cb < CIN / 32; ++cb) {
      short8 av0 = *(const short8*)(a0p + cb * 32);
      short8 av1 = *(const short8*)(a1p + cb * 32);
      av0 = v0 ? av0 : (short8)0;
      av1 = v1 ? av1 : (short8)0;
      #pragma unroll
      for (int nf = 0; nf < NFRAG; ++nf) {
        short8 bv = *(const short8*)(wp + (size_t)nf * 16 * CIN + cb * 32);
        acc[0][nf] = __builtin_amdgcn_mfma_f32_16x16x32_bf16(av0, bv, acc[0][nf], 0, 0, 0);
        acc[1][nf] = __builtin_amdgcn_mfma_f32_16x16x32_bf16(av1, bv, acc[1][nf], 0, 0, 0);
      }
    }
  }

  // epilogue: D lane mapping col(o)=lane&15, row(pixel)=(lane>>4)*4+reg
  unsigned short* ob = out + (size_t)b * HW_ * CROW;
  #pragma unroll
  for (int nf = 0; nf < NFRAG; ++nf) {
    const int o = nf * 16 + l15;
    const bool ov = (o < coutReal);
    const float bz = ov ? bias[o] : 0.f;
    #pragma unroll
    for (int mf = 0; mf < 2; ++mf) {
      #pragma unroll
      for (int r = 0; r < 4; ++r) {
        const int pix = m_base + mf * 16 + lg * 4 + r;
        float v = acc[mf][nf][r] + bz;
        if (LRELU) v = lrelu_f(v);
        if (ov) ob[(size_t)pix * CROW + o] = f2bf(v);
      }
    }
  }
}

// ---- DCNv1, o-split 4-way: wave = 16 output channels, lane = pixel ----
__global__ __launch_bounds__(256)
void dcn_k(const float* __restrict__ xin,        // [B][64][HW] fp32
           const unsigned short* __restrict__ offt, // [B][HW][72] bf16
           const float* __restrict__ wt,         // [(c*9+k)][64] fp32
           const float* __restrict__ bias, float* __restrict__ out) {
  const int lane = threadIdx.x & 63;
  const int wq = threadIdx.x >> 6;
  const int p = blockIdx.x * 64 + lane;
  const int b = blockIdx.y;
  const int y = p / WW, x = p % WW;
  const int o0 = __builtin_amdgcn_readfirstlane(wq * 16);

  float acc[16];
  #pragma unroll
  for (int i = 0; i < 16; ++i) acc[i] = bias[o0 + i];

  const float* xb = xin + (size_t)b * 64 * HW_;
  const unsigned short* orow = offt + ((size_t)b * HW_ + p) * 72;

  #pragma unroll 1
  for (int g = 0; g < 4; ++g) {
    #pragma unroll 1
    for (int k = 0; k < 9; ++k) {
      const float dy = bf2f(orow[g * 18 + 2 * k]);
      const float dx = bf2f(orow[g * 18 + 2 * k + 1]);
      const float sy = dy + (float)(y - 1 + k / 3);
      const float sx = dx + (float)(x - 1 + k % 3);
      const float fy = floorf(sy);
      const float fx = floorf(sx);
      const int y0 = (int)fy;
      const int x0 = (int)fx;
      const float ay = sy - fy;
      const float ax = sx - fx;
      float w00 = (1.f - ay) * (1.f - ax);
      float w01 = (1.f - ay) * ax;
      float w10 = ay * (1.f - ax);
      float w11 = ay * ax;
      const bool vy0 = (y0 >= 0) & (y0 < HH);
      const bool vy1 = (y0 + 1 >= 0) & (y0 + 1 < HH);
      const bool vx0 = (x0 >= 0) & (x0 < WW);
      const bool vx1 = (x0 + 1 >= 0) & (x0 + 1 < WW);
      w00 = (vy0 & vx0) ? w00 : 0.f;
      w01 = (vy0 & vx1) ? w01 : 0.f;
      w10 = (vy1 & vx0) ? w10 : 0.f;
      w11 = (vy1 & vx1) ? w11 : 0.f;
      const int cy0 = min(max(y0, 0), HH - 1);
      const int cy1 = min(max(y0 + 1, 0), HH - 1);
      const int cx0 = min(max(x0, 0), WW - 1);
      const int cx1 = min(max(x0 + 1, 0), WW - 1);
      const int i00 = cy0 * WW + cx0;
      const int i01 = cy0 * WW + cx1;
      const int i10 = cy1 * WW + cx0;
      const int i11 = cy1 * WW + cx1;
      const float* cb = xb + (size_t)g * 16 * HW_;
      #pragma unroll
      for (int c = 0; c < 16; ++c) {
        const float* ch = cb + (size_t)c * HW_;
        const float s = w00 * ch[i00] + w01 * ch[i01] + w10 * ch[i10] + w11 * ch[i11];
        const float* wck = wt + ((size_t)((g * 16 + c) * 9 + k)) * 64 + o0;
        #pragma unroll
        for (int i = 0; i < 16; ++i)
          acc[i] = fmaf(wck[i], s, acc[i]);
      }
    }
  }

  float* dst = out + ((size_t)b * 64 + o0) * HW_ + p;
  #pragma unroll
  for (int i = 0; i < 16; ++i)
    dst[(size_t)i * HW_] = lrelu_f(acc[i]);
}

extern "C" void kernel_launch(void* const* d_in, const int* in_sizes, int n_in,
                              void* d_out, int out_size, void* d_ws, size_t ws_size,
                              hipStream_t stream) {
  const float* nbr   = (const float*)d_in[0];
  const float* ref   = (const float*)d_in[1];
  const float* w_co1 = (const float*)d_in[2];
  const float* b_co1 = (const float*)d_in[3];
  const float* w_m1  = (const float*)d_in[4];
  const float* b_m1  = (const float*)d_in[5];
  const float* w_m2  = (const float*)d_in[6];
  const float* b_m2  = (const float*)d_in[7];
  const float* w_m3  = (const float*)d_in[8];
  const float* b_m3  = (const float*)d_in[9];
  const float* w_dcn = (const float*)d_in[10];
  const float* b_dcn = (const float*)d_in[11];
  float* out = (float*)d_out;

  char* ws = (char*)d_ws;
  // region0 [0, 29.36M): x1t [B][HW][128] bf16; later m2t [B][HW][64] bf16 aliases it
  // region12 [29.36M, 58.72M): featt [B][HW][64] + m1t [B][HW][64] bf16;
  //          later offt [B][HW][72] bf16 aliases its start (featt+m1t dead by then)
  // weights at 58.72M
  unsigned short* x1t   = (unsigned short*)(ws);
  unsigned short* m2t   = (unsigned short*)(ws);                    // alias
  unsigned short* featt = (unsigned short*)(ws + 29360128);
  unsigned short* m1t   = (unsigned short*)(ws + 29360128 + 14680064);
  unsigned short* offt  = (unsigned short*)(ws + 29360128);         // alias
  char* wbase = ws + 58720256;
  unsigned short* wt1  = (unsigned short*)(wbase);                  // 9*64*128*2 = 147456
  unsigned short* wtm1 = (unsigned short*)(wbase + 147456);         // 73728
  unsigned short* wtm2 = (unsigned short*)(wbase + 221184);         // 73728
  unsigned short* wtm3 = (unsigned short*)(wbase + 294912);         // 9*80*64*2 = 92160
  float*          wdt  = (float*)        (wbase + 387072);          // 147456

  dim3 blk(256);
  // weight preps
  prep_w<<<dim3(288), blk, 0, stream>>>(w_co1, wt1, 64, 64, 128);
  prep_w<<<dim3(144), blk, 0, stream>>>(w_m1, wtm1, 64, 64, 64);
  prep_w<<<dim3(144), blk, 0, stream>>>(w_m2, wtm2, 64, 64, 64);
  prep_w<<<dim3(180), blk, 0, stream>>>(w_m3, wtm3, 72, 80, 64);
  prep_wdcn<<<dim3(144), blk, 0, stream>>>(w_dcn, wdt);
  // input transpose+convert
  prep_xt<<<dim3(448, 4), blk, 0, stream>>>(nbr, ref, x1t);
  // conv chain (all channel-last bf16)
  conv_mfma<128, 4, 64, true ><<<dim3(224, 4), blk, 0, stream>>>(x1t,  wt1,  b_co1, featt, 64);
  conv_mfma< 64, 4, 64, true ><<<dim3(224, 4), blk, 0, stream>>>(featt, wtm1, b_m1,  m1t,   64);
  conv_mfma< 64, 4, 64, true ><<<dim3(224, 4), blk, 0, stream>>>(m1t,  wtm2, b_m2,  m2t,   64);
  conv_mfma< 64, 5, 72, false><<<dim3(224, 4), blk, 0, stream>>>(m2t,  wtm3, b_m3,  offt,  72);
  // deformable conv
  dcn_k<<<dim3(448, 4), blk, 0, stream>>>(nbr, offt, wdt, b_dcn, out);
}

// Round 3
// 481.036 us; speedup vs baseline: 2.6627x; 1.9167x over previous
//
#include <hip/hip_runtime.h>

#define HH 128
#define WW 224
#define HW_ (HH * WW)   // 28672

typedef short short8 __attribute__((ext_vector_type(8)));
typedef float f32x4 __attribute__((ext_vector_type(4)));

__device__ __forceinline__ float lrelu_f(float v) { return v >= 0.f ? v : 0.1f * v; }

__device__ __forceinline__ unsigned short f2bf(float f) {
  union { float f; unsigned u; } x; x.f = f;
  unsigned r = x.u + 0x7fff + ((x.u >> 16) & 1);   // RNE
  return (unsigned short)(r >> 16);
}
__device__ __forceinline__ float bf2f(unsigned short u) {
  union { unsigned u; float f; } x; x.u = ((unsigned)u) << 16; return x.f;
}

// ---- prep: concat(nbr,ref) -> channel-last bf16 x1t[b][p][128] ----
__global__ __launch_bounds__(256)
void prep_xt(const float* __restrict__ nbr, const float* __restrict__ ref,
             unsigned short* __restrict__ xt) {
  const int lane = threadIdx.x & 63;
  const int q = threadIdx.x >> 6;          // channel quarter (32 ch)
  const int p = blockIdx.x * 64 + lane;
  const int b = blockIdx.y;
  const int c0 = q * 32;
  const float* src = (c0 < 64) ? (nbr + ((size_t)b * 64 + c0) * HW_)
                               : (ref + ((size_t)b * 64 + (c0 - 64)) * HW_);
  unsigned short tmp[32];
  #pragma unroll
  for (int i = 0; i < 32; ++i) tmp[i] = f2bf(src[(size_t)i * HW_ + p]);
  unsigned short* dst = xt + ((size_t)b * HW_ + p) * 128 + c0;
  #pragma unroll
  for (int i = 0; i < 4; ++i)
    *(short8*)(dst + i * 8) = *(const short8*)(tmp + i * 8);
}

// ---- prep: conv weight [O][C][9] fp32 -> [9][Opad][C] bf16 (zero-pad o>=O) ----
__global__ void prep_w(const float* __restrict__ w, unsigned short* __restrict__ wt,
                       int O, int Opad, int C) {
  int idx = blockIdx.x * 256 + threadIdx.x;
  int total = Opad * C * 9;
  if (idx >= total) return;
  int c = idx % C;
  int o = (idx / C) % Opad;
  int k = idx / (C * Opad);
  float v = (o < O) ? w[((size_t)o * C + c) * 9 + k] : 0.f;
  wt[idx] = f2bf(v);
}

// ---- prep: dcn weight [O][C][9] fp32 -> bf16 [o][ (c/16)*144 + k*16 + c%16 ] ----
__global__ void prep_wdcn(const float* __restrict__ w, unsigned short* __restrict__ wt) {
  int i = blockIdx.x * 256 + threadIdx.x;
  if (i >= 64 * 64 * 9) return;
  const int k = i % 9;
  const int c = (i / 9) % 64;
  const int o = i / (9 * 64);
  wt[(size_t)o * 576 + (c / 16) * 144 + k * 16 + (c % 16)] = f2bf(w[i]);
}

// ---- implicit-GEMM 3x3 conv via MFMA. Block: 128 pixels x NFRAG*16 outputs ----
// xt: [b][p][CIN] bf16. wt: [9][NFRAG*16][CIN] bf16. out: [b][p][CROW] bf16.
template<int CIN, int NFRAG, int CROW, bool LRELU>
__global__ __launch_bounds__(256)
void conv_mfma(const unsigned short* __restrict__ xt, const unsigned short* __restrict__ wt,
               const float* __restrict__ bias, unsigned short* __restrict__ out, int coutReal) {
  const int lane = threadIdx.x & 63;
  const int wave = threadIdx.x >> 6;
  const int b = blockIdx.y;
  const int m_base = blockIdx.x * 128 + wave * 32;
  const int l15 = lane & 15;
  const int lg = lane >> 4;

  const int p0 = m_base + l15;
  const int p1 = p0 + 16;
  const int y0p = p0 / WW, x0p = p0 % WW;
  const int y1p = p1 / WW, x1p = p1 % WW;
  const unsigned short* xb = xt + (size_t)b * HW_ * CIN;

  f32x4 acc[2][NFRAG];
  #pragma unroll
  for (int mf = 0; mf < 2; ++mf)
    #pragma unroll
    for (int nf = 0; nf < NFRAG; ++nf) acc[mf][nf] = (f32x4){0.f, 0.f, 0.f, 0.f};

  #pragma unroll 1
  for (int k = 0; k < 9; ++k) {
    const int ky = k / 3 - 1, kx = k % 3 - 1;
    const bool v0 = ((unsigned)(y0p + ky) < HH) & ((unsigned)(x0p + kx) < WW);
    const bool v1 = ((unsigned)(y1p + ky) < HH) & ((unsigned)(x1p + kx) < WW);
    const int q0 = v0 ? (p0 + ky * WW + kx) : 0;
    const int q1 = v1 ? (p1 + ky * WW + kx) : 0;
    const unsigned short* a0p = xb + (size_t)q0 * CIN + lg * 8;
    const unsigned short* a1p = xb + (size_t)q1 * CIN + lg * 8;
    const unsigned short* wp = wt + ((size_t)k * (NFRAG * 16) + l15) * CIN + lg * 8;
    #pragma unroll
    for (int cb = 0; cb < CIN / 32; ++cb) {
      short8 av0 = *(const short8*)(a0p + cb * 32);
      short8 av1 = *(const short8*)(a1p + cb * 32);
      av0 = v0 ? av0 : (short8)0;
      av1 = v1 ? av1 : (short8)0;
      #pragma unroll
      for (int nf = 0; nf < NFRAG; ++nf) {
        short8 bv = *(const short8*)(wp + (size_t)nf * 16 * CIN + cb * 32);
        acc[0][nf] = __builtin_amdgcn_mfma_f32_16x16x32_bf16(av0, bv, acc[0][nf], 0, 0, 0);
        acc[1][nf] = __builtin_amdgcn_mfma_f32_16x16x32_bf16(av1, bv, acc[1][nf], 0, 0, 0);
      }
    }
  }

  unsigned short* ob = out + (size_t)b * HW_ * CROW;
  #pragma unroll
  for (int nf = 0; nf < NFRAG; ++nf) {
    const int o = nf * 16 + l15;
    const bool ov = (o < coutReal);
    const float bz = ov ? bias[o] : 0.f;
    #pragma unroll
    for (int mf = 0; mf < 2; ++mf) {
      #pragma unroll
      for (int r = 0; r < 4; ++r) {
        const int pix = m_base + mf * 16 + lg * 4 + r;
        float v = acc[mf][nf][r] + bz;
        if (LRELU) v = lrelu_f(v);
        if (ov) ob[(size_t)pix * CROW + o] = f2bf(v);
      }
    }
  }
}

// ---- fused DCN: sample -> LDS (bf16, XOR-swizzled) -> MFMA GEMM (K=576) ----
// Block: 512 threads (8 waves) = 64 pixels. Two K-halves (2 offset groups each).
#define LROW 640   // LDS row stride bytes (64 px rows; 160 dw => bank-aligned)
__global__ __launch_bounds__(512)
void dcn_fused(const float* __restrict__ xin,           // [B][64][HW] fp32
               const unsigned short* __restrict__ offt, // [B][HW][72] bf16
               const unsigned short* __restrict__ wdt,  // [64][576] bf16
               const float* __restrict__ bias, float* __restrict__ out) {
  __shared__ __align__(16) char smp[64 * LROW];  // 40960 B
  const int tid = threadIdx.x;
  const int w = tid >> 6, l = tid & 63;
  const int l15 = l & 15, lg = l >> 4;
  const int b = blockIdx.y;
  const int p_tile = blockIdx.x * 64;

  // phase-1 roles: gl = group-within-half, pixel quarter = w&3, c-quarter = lg
  const int gl = w >> 2;
  const int p1p = (w & 3) * 16 + l15;    // pixel within tile
  const int p_img = p_tile + p1p;
  const int y = p_img / WW, x = p_img % WW;
  const float* xb = xin + (size_t)b * 64 * HW_;

  // phase-2 roles
  const int o0 = (w & 3) * 16;
  const int mhalf = w >> 2;

  f32x4 acc[2];
  acc[0] = (f32x4){0.f, 0.f, 0.f, 0.f};
  acc[1] = (f32x4){0.f, 0.f, 0.f, 0.f};

  #pragma unroll 1
  for (int h = 0; h < 2; ++h) {
    // ---------- phase 1: sample group g = h*2+gl, channels cq*4..cq*4+3 ----------
    const int g = h * 2 + gl;
    const unsigned* od = (const unsigned*)(offt + ((size_t)b * HW_ + p_img) * 72 + g * 18);
    const float* cbase = xb + ((size_t)g * 16 + lg * 4) * HW_;
    #pragma unroll 3
    for (int k = 0; k < 9; ++k) {
      const unsigned dpair = od[k];
      const float dy = bf2f((unsigned short)(dpair & 0xffff));
      const float dx = bf2f((unsigned short)(dpair >> 16));
      const float sy = dy + (float)(y - 1 + k / 3);
      const float sx = dx + (float)(x - 1 + k % 3);
      const float fy = floorf(sy);
      const float fx = floorf(sx);
      const int y0 = (int)fy;
      const int x0 = (int)fx;
      const float ay = sy - fy;
      const float ax = sx - fx;
      float w00 = (1.f - ay) * (1.f - ax);
      float w01 = (1.f - ay) * ax;
      float w10 = ay * (1.f - ax);
      float w11 = ay * ax;
      const bool vy0 = (y0 >= 0) & (y0 < HH);
      const bool vy1 = (y0 + 1 >= 0) & (y0 + 1 < HH);
      const bool vx0 = (x0 >= 0) & (x0 < WW);
      const bool vx1 = (x0 + 1 >= 0) & (x0 + 1 < WW);
      w00 = (vy0 & vx0) ? w00 : 0.f;
      w01 = (vy0 & vx1) ? w01 : 0.f;
      w10 = (vy1 & vx0) ? w10 : 0.f;
      w11 = (vy1 & vx1) ? w11 : 0.f;
      const int cy0 = min(max(y0, 0), HH - 1);
      const int cy1 = min(max(y0 + 1, 0), HH - 1);
      const int cx0 = min(max(x0, 0), WW - 1);
      const int cx1 = min(max(x0 + 1, 0), WW - 1);
      const int i00 = cy0 * WW + cx0;
      const int i01 = cy0 * WW + cx1;
      const int i10 = cy1 * WW + cx0;
      const int i11 = cy1 * WW + cx1;
      unsigned short sv[4];
      #pragma unroll
      for (int j = 0; j < 4; ++j) {
        const float* ch = cbase + (size_t)j * HW_;
        const float s = w00 * ch[i00] + w01 * ch[i01] + w10 * ch[i10] + w11 * ch[i11];
        sv[j] = f2bf(s);
      }
      // LDS write: row p1p, byte (gl*9+k)*32 + cq*8, XOR-swizzled 16B units
      const int base = (gl * 9 + k) * 32 + lg * 8;
      const int sw = (base & ~0x70) | ((base ^ ((p1p & 7) << 4)) & 0x70);
      *(uint2*)(smp + p1p * LROW + sw) = *(const uint2*)sv;
    }
    __syncthreads();
    // ---------- phase 2: GEMM quarter-K (288) ----------
    const unsigned short* wrow = wdt + (size_t)(o0 + l15) * 576 + h * 288 + lg * 8;
    #pragma unroll
    for (int kb = 0; kb < 9; ++kb) {
      const short8 wf = *(const short8*)(wrow + kb * 32);
      #pragma unroll
      for (int mf = 0; mf < 2; ++mf) {
        const int prow = mhalf * 32 + mf * 16 + l15;
        const int byte = kb * 64 + lg * 16;
        const int sw = (byte & ~0x70) | ((byte ^ ((prow & 7) << 4)) & 0x70);
        const short8 pf = *(const short8*)(smp + prow * LROW + sw);
        acc[mf] = __builtin_amdgcn_mfma_f32_16x16x32_bf16(wf, pf, acc[mf], 0, 0, 0);
      }
    }
    __syncthreads();
  }

  // epilogue: D row = o (A=weights), col = pixel (B=pixels) -> pixel-coalesced store
  float* ob = out + (size_t)b * 64 * HW_;
  #pragma unroll
  for (int mf = 0; mf < 2; ++mf) {
    const int px = p_tile + mhalf * 32 + mf * 16 + l15;
    #pragma unroll
    for (int r = 0; r < 4; ++r) {
      const int o = o0 + lg * 4 + r;
      ob[(size_t)o * HW_ + px] = lrelu_f(acc[mf][r] + bias[o]);
    }
  }
}

extern "C" void kernel_launch(void* const* d_in, const int* in_sizes, int n_in,
                              void* d_out, int out_size, void* d_ws, size_t ws_size,
                              hipStream_t stream) {
  const float* nbr   = (const float*)d_in[0];
  const float* ref   = (const float*)d_in[1];
  const float* w_co1 = (const float*)d_in[2];
  const float* b_co1 = (const float*)d_in[3];
  const float* w_m1  = (const float*)d_in[4];
  const float* b_m1  = (const float*)d_in[5];
  const float* w_m2  = (const float*)d_in[6];
  const float* b_m2  = (const float*)d_in[7];
  const float* w_m3  = (const float*)d_in[8];
  const float* b_m3  = (const float*)d_in[9];
  const float* w_dcn = (const float*)d_in[10];
  const float* b_dcn = (const float*)d_in[11];
  float* out = (float*)d_out;

  char* ws = (char*)d_ws;
  unsigned short* x1t   = (unsigned short*)(ws);
  unsigned short* m2t   = (unsigned short*)(ws);                    // alias
  unsigned short* featt = (unsigned short*)(ws + 29360128);
  unsigned short* m1t   = (unsigned short*)(ws + 29360128 + 14680064);
  unsigned short* offt  = (unsigned short*)(ws + 29360128);         // alias
  char* wbase = ws + 58720256;
  unsigned short* wt1  = (unsigned short*)(wbase);                  // 147456
  unsigned short* wtm1 = (unsigned short*)(wbase + 147456);         // 73728
  unsigned short* wtm2 = (unsigned short*)(wbase + 221184);         // 73728
  unsigned short* wtm3 = (unsigned short*)(wbase + 294912);         // 92160
  unsigned short* wdt  = (unsigned short*)(wbase + 387072);         // 73728

  dim3 blk(256);
  prep_w<<<dim3(288), blk, 0, stream>>>(w_co1, wt1, 64, 64, 128);
  prep_w<<<dim3(144), blk, 0, stream>>>(w_m1, wtm1, 64, 64, 64);
  prep_w<<<dim3(144), blk, 0, stream>>>(w_m2, wtm2, 64, 64, 64);
  prep_w<<<dim3(180), blk, 0, stream>>>(w_m3, wtm3, 72, 80, 64);
  prep_wdcn<<<dim3(144), blk, 0, stream>>>(w_dcn, wdt);
  prep_xt<<<dim3(448, 4), blk, 0, stream>>>(nbr, ref, x1t);
  conv_mfma<128, 4, 64, true ><<<dim3(224, 4), blk, 0, stream>>>(x1t,  wt1,  b_co1, featt, 64);
  conv_mfma< 64, 4, 64, true ><<<dim3(224, 4), blk, 0, stream>>>(featt, wtm1, b_m1,  m1t,   64);
  conv_mfma< 64, 4, 64, true ><<<dim3(224, 4), blk, 0, stream>>>(m1t,  wtm2, b_m2,  m2t,   64);
  conv_mfma< 64, 5, 72, false><<<dim3(224, 4), blk, 0, stream>>>(m2t,  wtm3, b_m3,  offt,  72);
  dcn_fused<<<dim3(448, 4), dim3(512), 0, stream>>>(nbr, offt, wdt, b_dcn, out);
}

// Round 4
// 437.890 us; speedup vs baseline: 2.9251x; 1.0985x over previous
//
#include <hip/hip_runtime.h>

#define HH 128
#define WW 224
#define HW_ (HH * WW)   // 28672

typedef short short8 __attribute__((ext_vector_type(8)));
typedef float f32x4 __attribute__((ext_vector_type(4)));
typedef unsigned short ushort4v __attribute__((ext_vector_type(4)));

__device__ __forceinline__ float lrelu_f(float v) { return v >= 0.f ? v : 0.1f * v; }

__device__ __forceinline__ unsigned short f2bf(float f) {
  union { float f; unsigned u; } x; x.f = f;
  unsigned r = x.u + 0x7fff + ((x.u >> 16) & 1);   // RNE
  return (unsigned short)(r >> 16);
}
__device__ __forceinline__ float bf2f(unsigned short u) {
  union { unsigned u; float f; } x; x.u = ((unsigned)u) << 16; return x.f;
}

// ---- prep: concat(nbr,ref) -> channel-last bf16 x1t[b][p][128] ----
__global__ __launch_bounds__(256)
void prep_xt(const float* __restrict__ nbr, const float* __restrict__ ref,
             unsigned short* __restrict__ xt) {
  const int lane = threadIdx.x & 63;
  const int q = threadIdx.x >> 6;          // channel quarter (32 ch)
  const int p = blockIdx.x * 64 + lane;
  const int b = blockIdx.y;
  const int c0 = q * 32;
  const float* src = (c0 < 64) ? (nbr + ((size_t)b * 64 + c0) * HW_)
                               : (ref + ((size_t)b * 64 + (c0 - 64)) * HW_);
  unsigned short tmp[32];
  #pragma unroll
  for (int i = 0; i < 32; ++i) tmp[i] = f2bf(src[(size_t)i * HW_ + p]);
  unsigned short* dst = xt + ((size_t)b * HW_ + p) * 128 + c0;
  #pragma unroll
  for (int i = 0; i < 4; ++i)
    *(short8*)(dst + i * 8) = *(const short8*)(tmp + i * 8);
}

// ---- prep: conv weight [O][C][9] fp32 -> [9][Opad][C] bf16 (zero-pad o>=O) ----
__global__ void prep_w(const float* __restrict__ w, unsigned short* __restrict__ wt,
                       int O, int Opad, int C) {
  int idx = blockIdx.x * 256 + threadIdx.x;
  int total = Opad * C * 9;
  if (idx >= total) return;
  int c = idx % C;
  int o = (idx / C) % Opad;
  int k = idx / (C * Opad);
  float v = (o < O) ? w[((size_t)o * C + c) * 9 + k] : 0.f;
  wt[idx] = f2bf(v);
}

// ---- prep: dcn weight [O][C][9] fp32 -> bf16 [o][ (c/16)*144 + k*16 + c%16 ] ----
__global__ void prep_wdcn(const float* __restrict__ w, unsigned short* __restrict__ wt) {
  int i = blockIdx.x * 256 + threadIdx.x;
  if (i >= 64 * 64 * 9) return;
  const int k = i % 9;
  const int c = (i / 9) % 64;
  const int o = i / (9 * 64);
  wt[(size_t)o * 576 + (c / 16) * 144 + k * 16 + (c % 16)] = f2bf(w[i]);
}

// ---- implicit-GEMM 3x3 conv via MFMA. Block: 128 pixels x NFRAG*16 outputs ----
template<int CIN, int NFRAG, int CROW, bool LRELU>
__global__ __launch_bounds__(256)
void conv_mfma(const unsigned short* __restrict__ xt, const unsigned short* __restrict__ wt,
               const float* __restrict__ bias, unsigned short* __restrict__ out, int coutReal) {
  const int lane = threadIdx.x & 63;
  const int wave = threadIdx.x >> 6;
  const int b = blockIdx.y;
  const int m_base = blockIdx.x * 128 + wave * 32;
  const int l15 = lane & 15;
  const int lg = lane >> 4;

  const int p0 = m_base + l15;
  const int p1 = p0 + 16;
  const int y0p = p0 / WW, x0p = p0 % WW;
  const int y1p = p1 / WW, x1p = p1 % WW;
  const unsigned short* xb = xt + (size_t)b * HW_ * CIN;

  f32x4 acc[2][NFRAG];
  #pragma unroll
  for (int mf = 0; mf < 2; ++mf)
    #pragma unroll
    for (int nf = 0; nf < NFRAG; ++nf) acc[mf][nf] = (f32x4){0.f, 0.f, 0.f, 0.f};

  #pragma unroll 3
  for (int k = 0; k < 9; ++k) {
    const int ky = k / 3 - 1, kx = k % 3 - 1;
    const bool v0 = ((unsigned)(y0p + ky) < HH) & ((unsigned)(x0p + kx) < WW);
    const bool v1 = ((unsigned)(y1p + ky) < HH) & ((unsigned)(x1p + kx) < WW);
    const int q0 = v0 ? (p0 + ky * WW + kx) : 0;
    const int q1 = v1 ? (p1 + ky * WW + kx) : 0;
    const unsigned short* a0p = xb + (size_t)q0 * CIN + lg * 8;
    const unsigned short* a1p = xb + (size_t)q1 * CIN + lg * 8;
    const unsigned short* wp = wt + ((size_t)k * (NFRAG * 16) + l15) * CIN + lg * 8;
    #pragma unroll
    for (int cb = 0; cb < CIN / 32; ++cb) {
      short8 av0 = *(const short8*)(a0p + cb * 32);
      short8 av1 = *(const short8*)(a1p + cb * 32);
      av0 = v0 ? av0 : (short8)0;
      av1 = v1 ? av1 : (short8)0;
      #pragma unroll
      for (int nf = 0; nf < NFRAG; ++nf) {
        short8 bv = *(const short8*)(wp + (size_t)nf * 16 * CIN + cb * 32);
        acc[0][nf] = __builtin_amdgcn_mfma_f32_16x16x32_bf16(av0, bv, acc[0][nf], 0, 0, 0);
        acc[1][nf] = __builtin_amdgcn_mfma_f32_16x16x32_bf16(av1, bv, acc[1][nf], 0, 0, 0);
      }
    }
  }

  unsigned short* ob = out + (size_t)b * HW_ * CROW;
  #pragma unroll
  for (int nf = 0; nf < NFRAG; ++nf) {
    const int o = nf * 16 + l15;
    const bool ov = (o < coutReal);
    const float bz = ov ? bias[o] : 0.f;
    #pragma unroll
    for (int mf = 0; mf < 2; ++mf) {
      #pragma unroll
      for (int r = 0; r < 4; ++r) {
        const int pix = m_base + mf * 16 + lg * 4 + r;
        float v = acc[mf][nf][r] + bz;
        if (LRELU) v = lrelu_f(v);
        if (ov) ob[(size_t)pix * CROW + o] = f2bf(v);
      }
    }
  }
}

// ---- fused DCN: sample (channel-last bf16, 8B corner loads) -> LDS -> MFMA ----
#define LROW 640
__global__ __launch_bounds__(512)
void dcn_fused(const unsigned short* __restrict__ x1t,  // [B][HW][128] bf16 (ch 0-63 = nbr)
               const unsigned short* __restrict__ offt, // [B][HW][72] bf16
               const unsigned short* __restrict__ wdt,  // [64][576] bf16
               const float* __restrict__ bias, float* __restrict__ out) {
  __shared__ __align__(16) char smp[64 * LROW];  // 40960 B
  const int tid = threadIdx.x;
  const int w = tid >> 6, l = tid & 63;
  const int l15 = l & 15, lg = l >> 4;
  const int b = blockIdx.y;
  const int p_tile = blockIdx.x * 64;

  const int gl = w >> 2;
  const int p1p = (w & 3) * 16 + l15;
  const int p_img = p_tile + p1p;
  const int y = p_img / WW, x = p_img % WW;
  const unsigned short* xb = x1t + (size_t)b * HW_ * 128;

  const int o0 = (w & 3) * 16;
  const int mhalf = w >> 2;

  f32x4 acc[2];
  acc[0] = (f32x4){0.f, 0.f, 0.f, 0.f};
  acc[1] = (f32x4){0.f, 0.f, 0.f, 0.f};

  #pragma unroll 1
  for (int h = 0; h < 2; ++h) {
    // ---------- phase 1: sample group g = h*2+gl, channels g*16 + lg*4 .. +3 ----------
    const int g = h * 2 + gl;
    const int cofs = g * 16 + lg * 4;
    const unsigned* od = (const unsigned*)(offt + ((size_t)b * HW_ + p_img) * 72 + g * 18);
    unsigned odr[9];
    #pragma unroll
    for (int k = 0; k < 9; ++k) odr[k] = od[k];
    #pragma unroll 3
    for (int k = 0; k < 9; ++k) {
      const unsigned dpair = odr[k];
      const float dy = bf2f((unsigned short)(dpair & 0xffff));
      const float dx = bf2f((unsigned short)(dpair >> 16));
      const float sy = dy + (float)(y - 1 + k / 3);
      const float sx = dx + (float)(x - 1 + k % 3);
      const float fy = floorf(sy);
      const float fx = floorf(sx);
      const int y0 = (int)fy;
      const int x0 = (int)fx;
      const float ay = sy - fy;
      const float ax = sx - fx;
      float w00 = (1.f - ay) * (1.f - ax);
      float w01 = (1.f - ay) * ax;
      float w10 = ay * (1.f - ax);
      float w11 = ay * ax;
      const bool vy0 = (y0 >= 0) & (y0 < HH);
      const bool vy1 = (y0 + 1 >= 0) & (y0 + 1 < HH);
      const bool vx0 = (x0 >= 0) & (x0 < WW);
      const bool vx1 = (x0 + 1 >= 0) & (x0 + 1 < WW);
      w00 = (vy0 & vx0) ? w00 : 0.f;
      w01 = (vy0 & vx1) ? w01 : 0.f;
      w10 = (vy1 & vx0) ? w10 : 0.f;
      w11 = (vy1 & vx1) ? w11 : 0.f;
      const int cy0 = min(max(y0, 0), HH - 1);
      const int cy1 = min(max(y0 + 1, 0), HH - 1);
      const int cx0 = min(max(x0, 0), WW - 1);
      const int cx1 = min(max(x0 + 1, 0), WW - 1);
      // 4 corners x 4 channels: 8B loads from channel-last bf16
      const ushort4v q00 = *(const ushort4v*)(xb + ((size_t)(cy0 * WW + cx0)) * 128 + cofs);
      const ushort4v q01 = *(const ushort4v*)(xb + ((size_t)(cy0 * WW + cx1)) * 128 + cofs);
      const ushort4v q10 = *(const ushort4v*)(xb + ((size_t)(cy1 * WW + cx0)) * 128 + cofs);
      const ushort4v q11 = *(const ushort4v*)(xb + ((size_t)(cy1 * WW + cx1)) * 128 + cofs);
      unsigned short sv[4];
      #pragma unroll
      for (int j = 0; j < 4; ++j) {
        const float s = w00 * bf2f(q00[j]) + w01 * bf2f(q01[j])
                      + w10 * bf2f(q10[j]) + w11 * bf2f(q11[j]);
        sv[j] = f2bf(s);
      }
      const int base = (gl * 9 + k) * 32 + lg * 8;
      const int sw = (base & ~0x70) | ((base ^ ((p1p & 7) << 4)) & 0x70);
      *(uint2*)(smp + p1p * LROW + sw) = *(const uint2*)sv;
    }
    __syncthreads();
    // ---------- phase 2: GEMM quarter-K (288) ----------
    const unsigned short* wrow = wdt + (size_t)(o0 + l15) * 576 + h * 288 + lg * 8;
    #pragma unroll
    for (int kb = 0; kb < 9; ++kb) {
      const short8 wf = *(const short8*)(wrow + kb * 32);
      #pragma unroll
      for (int mf = 0; mf < 2; ++mf) {
        const int prow = mhalf * 32 + mf * 16 + l15;
        const int byte = kb * 64 + lg * 16;
        const int sw = (byte & ~0x70) | ((byte ^ ((prow & 7) << 4)) & 0x70);
        const short8 pf = *(const short8*)(smp + prow * LROW + sw);
        acc[mf] = __builtin_amdgcn_mfma_f32_16x16x32_bf16(wf, pf, acc[mf], 0, 0, 0);
      }
    }
    __syncthreads();
  }

  float* ob = out + (size_t)b * 64 * HW_;
  #pragma unroll
  for (int mf = 0; mf < 2; ++mf) {
    const int px = p_tile + mhalf * 32 + mf * 16 + l15;
    #pragma unroll
    for (int r = 0; r < 4; ++r) {
      const int o = o0 + lg * 4 + r;
      ob[(size_t)o * HW_ + px] = lrelu_f(acc[mf][r] + bias[o]);
    }
  }
}

extern "C" void kernel_launch(void* const* d_in, const int* in_sizes, int n_in,
                              void* d_out, int out_size, void* d_ws, size_t ws_size,
                              hipStream_t stream) {
  const float* nbr   = (const float*)d_in[0];
  const float* ref   = (const float*)d_in[1];
  const float* w_co1 = (const float*)d_in[2];
  const float* b_co1 = (const float*)d_in[3];
  const float* w_m1  = (const float*)d_in[4];
  const float* b_m1  = (const float*)d_in[5];
  const float* w_m2  = (const float*)d_in[6];
  const float* b_m2  = (const float*)d_in[7];
  const float* w_m3  = (const float*)d_in[8];
  const float* b_m3  = (const float*)d_in[9];
  const float* w_dcn = (const float*)d_in[10];
  const float* b_dcn = (const float*)d_in[11];
  float* out = (float*)d_out;

  char* ws = (char*)d_ws;
  // x1t [B][HW][128] bf16: [0, 29.36M)            -- persistent (dcn samples it)
  // featt: [29.36M, 44.04M)  -> later m2t aliases it
  // m1t:   [44.04M, 58.72M)  -> later offt aliases it (offt = 16.5MB, to 60.55M)
  // weights at 60.56M
  unsigned short* x1t   = (unsigned short*)(ws);
  unsigned short* featt = (unsigned short*)(ws + 29360128);
  unsigned short* m1t   = (unsigned short*)(ws + 44040192);
  unsigned short* m2t   = (unsigned short*)(ws + 29360128);   // alias featt
  unsigned short* offt  = (unsigned short*)(ws + 44040192);   // alias m1t (16.5MB)
  char* wbase = ws + 60555264;
  unsigned short* wt1  = (unsigned short*)(wbase);            // 147456
  unsigned short* wtm1 = (unsigned short*)(wbase + 147456);   // 73728
  unsigned short* wtm2 = (unsigned short*)(wbase + 221184);   // 73728
  unsigned short* wtm3 = (unsigned short*)(wbase + 294912);   // 92160
  unsigned short* wdt  = (unsigned short*)(wbase + 387072);   // 73728

  dim3 blk(256);
  prep_w<<<dim3(288), blk, 0, stream>>>(w_co1, wt1, 64, 64, 128);
  prep_w<<<dim3(144), blk, 0, stream>>>(w_m1, wtm1, 64, 64, 64);
  prep_w<<<dim3(144), blk, 0, stream>>>(w_m2, wtm2, 64, 64, 64);
  prep_w<<<dim3(180), blk, 0, stream>>>(w_m3, wtm3, 72, 80, 64);
  prep_wdcn<<<dim3(144), blk, 0, stream>>>(w_dcn, wdt);
  prep_xt<<<dim3(448, 4), blk, 0, stream>>>(nbr, ref, x1t);
  conv_mfma<128, 4, 64, true ><<<dim3(224, 4), blk, 0, stream>>>(x1t,   wt1,  b_co1, featt, 64);
  conv_mfma< 64, 4, 64, true ><<<dim3(224, 4), blk, 0, stream>>>(featt, wtm1, b_m1,  m1t,   64);
  conv_mfma< 64, 4, 64, true ><<<dim3(224, 4), blk, 0, stream>>>(m1t,   wtm2, b_m2,  m2t,   64);
  conv_mfma< 64, 5, 72, false><<<dim3(224, 4), blk, 0, stream>>>(m2t,   wtm3, b_m3,  offt,  72);
  dcn_fused<<<dim3(448, 4), dim3(512), 0, stream>>>(x1t, offt, wdt, b_dcn, out);
}

// Round 5
// 384.514 us; speedup vs baseline: 3.3311x; 1.1388x over previous
//
#include <hip/hip_runtime.h>

#define HH 128
#define WW 224
#define HW_ (HH * WW)   // 28672

typedef short short8 __attribute__((ext_vector_type(8)));
typedef float f32x4 __attribute__((ext_vector_type(4)));
typedef unsigned short ushort4v __attribute__((ext_vector_type(4)));

__device__ __forceinline__ float lrelu_f(float v) { return v >= 0.f ? v : 0.1f * v; }

__device__ __forceinline__ unsigned short f2bf(float f) {
  union { float f; unsigned u; } x; x.f = f;
  unsigned r = x.u + 0x7fff + ((x.u >> 16) & 1);   // RNE
  return (unsigned short)(r >> 16);
}
__device__ __forceinline__ float bf2f(unsigned short u) {
  union { unsigned u; float f; } x; x.u = ((unsigned)u) << 16; return x.f;
}

// ---- prep: concat(nbr,ref) -> channel-last bf16 x1t[b][p][128] ----
__global__ __launch_bounds__(256)
void prep_xt(const float* __restrict__ nbr, const float* __restrict__ ref,
             unsigned short* __restrict__ xt) {
  const int lane = threadIdx.x & 63;
  const int q = threadIdx.x >> 6;          // channel quarter (32 ch)
  const int p = blockIdx.x * 64 + lane;
  const int b = blockIdx.y;
  const int c0 = q * 32;
  const float* src = (c0 < 64) ? (nbr + ((size_t)b * 64 + c0) * HW_)
                               : (ref + ((size_t)b * 64 + (c0 - 64)) * HW_);
  unsigned short tmp[32];
  #pragma unroll
  for (int i = 0; i < 32; ++i) tmp[i] = f2bf(src[(size_t)i * HW_ + p]);
  unsigned short* dst = xt + ((size_t)b * HW_ + p) * 128 + c0;
  #pragma unroll
  for (int i = 0; i < 4; ++i)
    *(short8*)(dst + i * 8) = *(const short8*)(tmp + i * 8);
}

// ---- prep: conv weight [O][C][9] fp32 -> [9][Opad][C] bf16 (zero-pad o>=O) ----
__global__ void prep_w(const float* __restrict__ w, unsigned short* __restrict__ wt,
                       int O, int Opad, int C) {
  int idx = blockIdx.x * 256 + threadIdx.x;
  int total = Opad * C * 9;
  if (idx >= total) return;
  int c = idx % C;
  int o = (idx / C) % Opad;
  int k = idx / (C * Opad);
  float v = (o < O) ? w[((size_t)o * C + c) * 9 + k] : 0.f;
  wt[idx] = f2bf(v);
}

// ---- prep: dcn weight [O][C][9] fp32 -> bf16 [o][ (c/16)*144 + k*16 + c%16 ] ----
__global__ void prep_wdcn(const float* __restrict__ w, unsigned short* __restrict__ wt) {
  int i = blockIdx.x * 256 + threadIdx.x;
  if (i >= 64 * 64 * 9) return;
  const int k = i % 9;
  const int c = (i / 9) % 64;
  const int o = i / (9 * 64);
  wt[(size_t)o * 576 + (c / 16) * 144 + k * 16 + (c % 16)] = f2bf(w[i]);
}

// ---- implicit-GEMM 3x3 conv via MFMA. Wave: 64 pixels x NFRAG*16 outputs ----
// Block: 256 threads (4 waves) = 256 pixels. xt: [b][p][CIN] bf16.
// wt: [9][NFRAG*16][CIN] bf16. out: [b][p][CROW] bf16.
template<int CIN, int NFRAG, int CROW, bool LRELU>
__global__ __launch_bounds__(256)
void conv_mfma(const unsigned short* __restrict__ xt, const unsigned short* __restrict__ wt,
               const float* __restrict__ bias, unsigned short* __restrict__ out, int coutReal) {
  const int lane = threadIdx.x & 63;
  const int wave = threadIdx.x >> 6;
  const int b = blockIdx.y;
  const int m_base = blockIdx.x * 256 + wave * 64;
  const int l15 = lane & 15;
  const int lg = lane >> 4;

  int yy[4], xx[4];
  #pragma unroll
  for (int mf = 0; mf < 4; ++mf) {
    const int pp = m_base + mf * 16 + l15;
    yy[mf] = pp / WW;
    xx[mf] = pp % WW;
  }
  const unsigned short* xb = xt + (size_t)b * HW_ * CIN;

  f32x4 acc[4][NFRAG];
  #pragma unroll
  for (int mf = 0; mf < 4; ++mf)
    #pragma unroll
    for (int nf = 0; nf < NFRAG; ++nf) acc[mf][nf] = (f32x4){0.f, 0.f, 0.f, 0.f};

  #pragma unroll 3
  for (int k = 0; k < 9; ++k) {
    const int ky = k / 3 - 1, kx = k % 3 - 1;
    bool v[4];
    int q[4];
    #pragma unroll
    for (int mf = 0; mf < 4; ++mf) {
      v[mf] = ((unsigned)(yy[mf] + ky) < HH) & ((unsigned)(xx[mf] + kx) < WW);
      q[mf] = v[mf] ? (m_base + mf * 16 + l15 + ky * WW + kx) : 0;
    }
    const unsigned short* wp = wt + ((size_t)k * (NFRAG * 16) + l15) * CIN + lg * 8;
    #pragma unroll
    for (int cb = 0; cb < CIN / 32; ++cb) {
      short8 av[4];
      #pragma unroll
      for (int mf = 0; mf < 4; ++mf) {
        short8 a = *(const short8*)(xb + (size_t)q[mf] * CIN + lg * 8 + cb * 32);
        av[mf] = v[mf] ? a : (short8)0;
      }
      #pragma unroll
      for (int nf = 0; nf < NFRAG; ++nf) {
        const short8 bv = *(const short8*)(wp + (size_t)nf * 16 * CIN + cb * 32);
        #pragma unroll
        for (int mf = 0; mf < 4; ++mf)
          acc[mf][nf] = __builtin_amdgcn_mfma_f32_16x16x32_bf16(av[mf], bv, acc[mf][nf], 0, 0, 0);
      }
    }
  }

  unsigned short* ob = out + (size_t)b * HW_ * CROW;
  #pragma unroll
  for (int nf = 0; nf < NFRAG; ++nf) {
    const int o = nf * 16 + l15;
    const bool ov = (o < coutReal);
    const float bz = ov ? bias[o] : 0.f;
    #pragma unroll
    for (int mf = 0; mf < 4; ++mf) {
      #pragma unroll
      for (int r = 0; r < 4; ++r) {
        const int pix = m_base + mf * 16 + lg * 4 + r;
        float vv = acc[mf][nf][r] + bz;
        if (LRELU) vv = lrelu_f(vv);
        if (ov) ob[(size_t)pix * CROW + o] = f2bf(vv);
      }
    }
  }
}

// ---- fused DCN: sample (channel-last bf16, 8B corner loads) -> LDS -> MFMA ----
#define LROW 640
__global__ __launch_bounds__(512)
void dcn_fused(const unsigned short* __restrict__ x1t,  // [B][HW][128] bf16 (ch 0-63 = nbr)
               const unsigned short* __restrict__ offt, // [B][HW][72] bf16
               const unsigned short* __restrict__ wdt,  // [64][576] bf16
               const float* __restrict__ bias, float* __restrict__ out) {
  __shared__ __align__(16) char smp[64 * LROW];  // 40960 B
  const int tid = threadIdx.x;
  const int w = tid >> 6, l = tid & 63;
  const int l15 = l & 15, lg = l >> 4;
  const int b = blockIdx.y;
  const int p_tile = blockIdx.x * 64;

  const int gl = w >> 2;
  const int p1p = (w & 3) * 16 + l15;
  const int p_img = p_tile + p1p;
  const int y = p_img / WW, x = p_img % WW;
  const unsigned short* xb = x1t + (size_t)b * HW_ * 128;

  const int o0 = (w & 3) * 16;
  const int mhalf = w >> 2;

  f32x4 acc[2];
  acc[0] = (f32x4){0.f, 0.f, 0.f, 0.f};
  acc[1] = (f32x4){0.f, 0.f, 0.f, 0.f};

  #pragma unroll 1
  for (int h = 0; h < 2; ++h) {
    // ---------- phase 1: sample group g = h*2+gl, channels g*16 + lg*4 .. +3 ----------
    const int g = h * 2 + gl;
    const int cofs = g * 16 + lg * 4;
    const unsigned* od = (const unsigned*)(offt + ((size_t)b * HW_ + p_img) * 72 + g * 18);
    unsigned odr[9];
    #pragma unroll
    for (int k = 0; k < 9; ++k) odr[k] = od[k];
    #pragma unroll
    for (int k = 0; k < 9; ++k) {
      const unsigned dpair = odr[k];
      const float dy = bf2f((unsigned short)(dpair & 0xffff));
      const float dx = bf2f((unsigned short)(dpair >> 16));
      const float sy = dy + (float)(y - 1 + k / 3);
      const float sx = dx + (float)(x - 1 + k % 3);
      const float fy = floorf(sy);
      const float fx = floorf(sx);
      const int y0 = (int)fy;
      const int x0 = (int)fx;
      const float ay = sy - fy;
      const float ax = sx - fx;
      float w00 = (1.f - ay) * (1.f - ax);
      float w01 = (1.f - ay) * ax;
      float w10 = ay * (1.f - ax);
      float w11 = ay * ax;
      const bool vy0 = (y0 >= 0) & (y0 < HH);
      const bool vy1 = (y0 + 1 >= 0) & (y0 + 1 < HH);
      const bool vx0 = (x0 >= 0) & (x0 < WW);
      const bool vx1 = (x0 + 1 >= 0) & (x0 + 1 < WW);
      w00 = (vy0 & vx0) ? w00 : 0.f;
      w01 = (vy0 & vx1) ? w01 : 0.f;
      w10 = (vy1 & vx0) ? w10 : 0.f;
      w11 = (vy1 & vx1) ? w11 : 0.f;
      const int cy0 = min(max(y0, 0), HH - 1);
      const int cy1 = min(max(y0 + 1, 0), HH - 1);
      const int cx0 = min(max(x0, 0), WW - 1);
      const int cx1 = min(max(x0 + 1, 0), WW - 1);
      const ushort4v q00 = *(const ushort4v*)(xb + ((size_t)(cy0 * WW + cx0)) * 128 + cofs);
      const ushort4v q01 = *(const ushort4v*)(xb + ((size_t)(cy0 * WW + cx1)) * 128 + cofs);
      const ushort4v q10 = *(const ushort4v*)(xb + ((size_t)(cy1 * WW + cx0)) * 128 + cofs);
      const ushort4v q11 = *(const ushort4v*)(xb + ((size_t)(cy1 * WW + cx1)) * 128 + cofs);
      unsigned short sv[4];
      #pragma unroll
      for (int j = 0; j < 4; ++j) {
        const float s = w00 * bf2f(q00[j]) + w01 * bf2f(q01[j])
                      + w10 * bf2f(q10[j]) + w11 * bf2f(q11[j]);
        sv[j] = f2bf(s);
      }
      const int base = (gl * 9 + k) * 32 + lg * 8;
      const int sw = (base & ~0x70) | ((base ^ ((p1p & 7) << 4)) & 0x70);
      *(uint2*)(smp + p1p * LROW + sw) = *(const uint2*)sv;
    }
    __syncthreads();
    // ---------- phase 2: GEMM quarter-K (288) ----------
    const unsigned short* wrow = wdt + (size_t)(o0 + l15) * 576 + h * 288 + lg * 8;
    #pragma unroll
    for (int kb = 0; kb < 9; ++kb) {
      const short8 wf = *(const short8*)(wrow + kb * 32);
      #pragma unroll
      for (int mf = 0; mf < 2; ++mf) {
        const int prow = mhalf * 32 + mf * 16 + l15;
        const int byte = kb * 64 + lg * 16;
        const int sw = (byte & ~0x70) | ((byte ^ ((prow & 7) << 4)) & 0x70);
        const short8 pf = *(const short8*)(smp + prow * LROW + sw);
        acc[mf] = __builtin_amdgcn_mfma_f32_16x16x32_bf16(wf, pf, acc[mf], 0, 0, 0);
      }
    }
    __syncthreads();
  }

  float* ob = out + (size_t)b * 64 * HW_;
  #pragma unroll
  for (int mf = 0; mf < 2; ++mf) {
    const int px = p_tile + mhalf * 32 + mf * 16 + l15;
    #pragma unroll
    for (int r = 0; r < 4; ++r) {
      const int o = o0 + lg * 4 + r;
      ob[(size_t)o * HW_ + px] = lrelu_f(acc[mf][r] + bias[o]);
    }
  }
}

extern "C" void kernel_launch(void* const* d_in, const int* in_sizes, int n_in,
                              void* d_out, int out_size, void* d_ws, size_t ws_size,
                              hipStream_t stream) {
  const float* nbr   = (const float*)d_in[0];
  const float* ref   = (const float*)d_in[1];
  const float* w_co1 = (const float*)d_in[2];
  const float* b_co1 = (const float*)d_in[3];
  const float* w_m1  = (const float*)d_in[4];
  const float* b_m1  = (const float*)d_in[5];
  const float* w_m2  = (const float*)d_in[6];
  const float* b_m2  = (const float*)d_in[7];
  const float* w_m3  = (const float*)d_in[8];
  const float* b_m3  = (const float*)d_in[9];
  const float* w_dcn = (const float*)d_in[10];
  const float* b_dcn = (const float*)d_in[11];
  float* out = (float*)d_out;

  char* ws = (char*)d_ws;
  // x1t [B][HW][128] bf16: [0, 29.36M)            -- persistent (dcn samples it)
  // featt: [29.36M, 44.04M)  -> later m2t aliases it
  // m1t:   [44.04M, 58.72M)  -> later offt aliases it (offt = 16.5MB, to 60.55M)
  // weights at 60.56M
  unsigned short* x1t   = (unsigned short*)(ws);
  unsigned short* featt = (unsigned short*)(ws + 29360128);
  unsigned short* m1t   = (unsigned short*)(ws + 44040192);
  unsigned short* m2t   = (unsigned short*)(ws + 29360128);   // alias featt
  unsigned short* offt  = (unsigned short*)(ws + 44040192);   // alias m1t (16.5MB)
  char* wbase = ws + 60555264;
  unsigned short* wt1  = (unsigned short*)(wbase);            // 147456
  unsigned short* wtm1 = (unsigned short*)(wbase + 147456);   // 73728
  unsigned short* wtm2 = (unsigned short*)(wbase + 221184);   // 73728
  unsigned short* wtm3 = (unsigned short*)(wbase + 294912);   // 92160
  unsigned short* wdt  = (unsigned short*)(wbase + 387072);   // 73728

  dim3 blk(256);
  prep_w<<<dim3(288), blk, 0, stream>>>(w_co1, wt1, 64, 64, 128);
  prep_w<<<dim3(144), blk, 0, stream>>>(w_m1, wtm1, 64, 64, 64);
  prep_w<<<dim3(144), blk, 0, stream>>>(w_m2, wtm2, 64, 64, 64);
  prep_w<<<dim3(180), blk, 0, stream>>>(w_m3, wtm3, 72, 80, 64);
  prep_wdcn<<<dim3(144), blk, 0, stream>>>(w_dcn, wdt);
  prep_xt<<<dim3(448, 4), blk, 0, stream>>>(nbr, ref, x1t);
  conv_mfma<128, 4, 64, true ><<<dim3(112, 4), blk, 0, stream>>>(x1t,   wt1,  b_co1, featt, 64);
  conv_mfma< 64, 4, 64, true ><<<dim3(112, 4), blk, 0, stream>>>(featt, wtm1, b_m1,  m1t,   64);
  conv_mfma< 64, 4, 64, true ><<<dim3(112, 4), blk, 0, stream>>>(m1t,   wtm2, b_m2,  m2t,   64);
  conv_mfma< 64, 5, 72, false><<<dim3(112, 4), blk, 0, stream>>>(m2t,   wtm3, b_m3,  offt,  72);
  dcn_fused<<<dim3(448, 4), dim3(512), 0, stream>>>(x1t, offt, wdt, b_dcn, out);
}